// Round 8
// baseline (260.046 us; speedup 1.0000x reference)
//
#include <hip/hip_runtime.h>

// LIF spiking layer forward: x (B,C,T) fp32 -> spikes (B,C,T) fp32.
// Recurrence per row r=(b,c):
//   rst   = spk_{t-1} * Vth[c]
//   mem_t = (mem_{t-1} - rst)*beta + x_t*alpha
//   spk_t = (mem_t - Vth[c] > 0) ? 1 : 0
// Bit-exact vs numpy: no FMA contraction; rst via select (1.0*Vth == Vth,
// mem - 0.0 == mem).
//
// R1: occupancy structurally 1 wave/CU (16384 rows = 256 waves).
// R2: nt stores -> 3.5x write amplification. Reverted.
// R3: asm-VGPR loads + counted vmcnt, no LDS: 97.6 us, bit-exact.
// R4: asm stores consuming compiler ds_reads -> garbage. Never again.
// R5/R7: asm-VGPR loads + LDS transpose -> abort (2x). Diagnosis: the
//     allocator may copy/spill an asm-load output BEFORE the hardware write
//     lands (it has no vmcnt model for asm); the late write then corrupts a
//     reallocated register (e.g. a store address) -> wild access. Asm loads
//     with VGPR destinations are unusable under register pressure.
// R6: pure-C++ LDS transpose: PASSED, 89 us; VGPR=56 -> compiler collapsed
//     the prefetch again (3rd time). Store-request theory mostly dead.
// R8: prefetch WITHOUT VGPR destinations: __builtin_amdgcn_global_load_lds
//     (VMEM op, increments vmcnt, NO dest register -> nothing to spill;
//     compiler-modeled -> cannot cross my "memory"-clobber waits). x lands
//     in LDS at wave-uniform base + lane*16, which matches our per-lane
//     consumption exactly. Counted WAITV discipline identical to R3.
//     Compute/transpose/store path byte-identical to passing R6. 3 x-buffers,
//     prefetch distance 2.

constexpr int T_LEN = 2000;
constexpr int CH    = 32;                      // timesteps per full tile
constexpr int NQ    = CH / 4;                  // 8 glds instrs per tile
constexpr int NFULL = 62;                      // 62*32 = 1984
constexpr int TAILQ = (T_LEN - NFULL * CH)/4;  // 4 quads = 16 steps
constexpr int LDSW  = 33;                      // transpose row stride (dwords)
constexpr int XBUF  = NQ * 256;                // dwords per x-buffer (8 KB)

typedef float nfloat4 __attribute__((ext_vector_type(4)));

// Counted wait; "memory" fences all compiler memory ops AND the glds builtin
// (it has memory side effects) inside their region; sched_barrier stops
// hoisting of register-only consumers (guide rule #18).
#define WAITV(N) do { \
    asm volatile("s_waitcnt vmcnt(" #N ")" ::: "memory"); \
    __builtin_amdgcn_sched_barrier(0); } while (0)

// Direct global->LDS: lane L's 16B land at (wave-uniform lp) + L*16.
__device__ __forceinline__ void glds16(const float* gp, float* lp) {
    __builtin_amdgcn_global_load_lds(
        (const __attribute__((address_space(1))) void*)gp,
        (__attribute__((address_space(3))) void*)lp, 16, 0, 0);
}

// Issue N glds for one tile: instr q covers timesteps q*4..q*4+3 of every
// lane's row; lands at xb[q*256 + lane*4 + j].
template <int N>
__device__ __forceinline__ void load_tile(const float* xlt, float* xb) {
#pragma unroll
    for (int q = 0; q < N; ++q) glds16(xlt + q * 4, xb + q * 256);
}

__device__ __forceinline__ float lif_step(float xval, float alpha, float beta, float vth,
                                          float& mem, float& vdiff, bool& spk) {
#pragma clang fp contract(off)
    float xa = xval * alpha;             // x_t * alpha (separate mul, like np)
    // Speculative both-branch update; bit-exact vs (mem - rst)*beta + xa:
    //   spk==1: rst = 1.0*Vth = Vth, mem-Vth == vdiff (from last step)
    //   spk==0: rst = 0.0*Vth = 0.0, mem-0.0 == mem
    float p0 = mem   * beta;
    float p1 = vdiff * beta;
    float q0 = p0 + xa;
    float q1 = p1 + xa;
    mem   = spk ? q1 : q0;
    vdiff = mem - vth;
    spk   = vdiff > 0.0f;
    return spk ? 1.0f : 0.0f;
}

// Plain ds_read of this lane's N quads from an x-buffer (lgkmcnt managed by
// the compiler; ordered vs glds by the preceding WAITV's memory clobber).
template <int N>
__device__ __forceinline__ void read_x(nfloat4 (&xv)[NQ], const float* xrd) {
#pragma unroll
    for (int q = 0; q < N; ++q)
        xv[q] = *reinterpret_cast<const nfloat4*>(xrd + q * 256);
}

// lif over N quads; spikes into this lane's transpose row (stride-33:
// worst 2-way banking = free). Single wave: DS ops in order, no barrier.
template <int N>
__device__ __forceinline__ void lif_tile(const nfloat4 (&xv)[NQ], float* shrow,
                                         float alpha, float beta, float vth,
                                         float& mem, float& vdiff, bool& spk) {
#pragma clang fp contract(off)
#pragma unroll
    for (int q = 0; q < N; ++q) {
        shrow[q*4 + 0] = lif_step(xv[q].x, alpha, beta, vth, mem, vdiff, spk);
        shrow[q*4 + 1] = lif_step(xv[q].y, alpha, beta, vth, mem, vdiff, spk);
        shrow[q*4 + 2] = lif_step(xv[q].z, alpha, beta, vth, mem, vdiff, spk);
        shrow[q*4 + 3] = lif_step(xv[q].w, alpha, beta, vth, mem, vdiff, spk);
    }
}

// Transposed coalesced store (IDENTICAL to passing R6): instr k writes rows
// sub+8k (sub=0..7), each 128B contiguous. Exactly 8 vmem stores.
__device__ __forceinline__ void store_tile(const float* __restrict__ sh, int sub, int off,
                                           float* __restrict__ op) {
#pragma unroll
    for (int k = 0; k < 8; ++k) {
        const float* p = sh + (sub + 8*k) * LDSW + off * 4;
        float4 s = make_float4(p[0], p[1], p[2], p[3]);
        *reinterpret_cast<float4*>(op + (size_t)(8*k) * T_LEN) = s;
    }
}

__global__ __launch_bounds__(64) void lif_fwd_kernel(const float* __restrict__ x,
                                                     const float* __restrict__ alpha_p,
                                                     const float* __restrict__ beta_p,
                                                     const float* __restrict__ vth_p,
                                                     float* __restrict__ out,
                                                     int C, int rows) {
#pragma clang fp contract(off)
    // Requires rows % 64 == 0 (true: B*C = 16384).
    __shared__ float shx[3 * XBUF];                 // 24576 B: 3 x-buffers
    __shared__ float sh[64 * LDSW];                 // 8448 B: spike transpose

    const int lane = threadIdx.x;
    const int row0 = blockIdx.x * 64;
    const int row  = row0 + lane;
    if (row >= rows) return;

    const float alpha = alpha_p[0];
    const float beta  = beta_p[0];
    const float vth   = vth_p[(unsigned)row % (unsigned)C];
    // Materialize (and vmcnt-drain) all scalar loads HERE so manual vmcnt
    // counting starts from zero outstanding. (R3-proven.)
    asm volatile("" :: "v"(alpha), "v"(beta), "v"(vth));

    const float* xl  = x + (size_t)row * T_LEN;     // per-lane global base
    const float* xrd = shx + lane * 4;              // per-lane LDS read base
    float* __restrict__ shrow = sh + lane * LDSW;   // transpose write row
    const int sub = lane >> 3;                      // 0..7: row-in-group
    const int off = lane & 7;                       // 0..7: 16B column
    float* __restrict__ outp = out + (size_t)(row0 + sub) * T_LEN + off * 4;

    float mem = 0.0f, vdiff = 0.0f;
    bool  spk = false;                              // vdiff only read when spk
    nfloat4 xv[NQ];

    // vmcnt region totals are exact: glds = 8 (or 4 tail) VMEM ops,
    // store_tile = exactly 8 VMEM stores; nothing crosses a WAITV (memory
    // clobber both sides). In-order retirement -> counted waits valid even
    // if ops reorder WITHIN a region.
    load_tile<NQ>(xl,            shx + 0 * XBUF);   // L(0)
    load_tile<NQ>(xl + CH,       shx + 1 * XBUF);   // L(1)

    // body(0): after L(0): L(1)=8 outstanding allowed.
    WAITV(8);
    read_x<NQ>(xv, xrd + 0 * XBUF);
    load_tile<NQ>(xl + 2 * CH,   shx + 2 * XBUF);   // L(2)
    lif_tile<NQ>(xv, shrow, alpha, beta, vth, mem, vdiff, spk);
    store_tile(sh, sub, off, outp);                 // S(0)

    // bodies t=1..59: after L(t): [S(t-2)] L(t+1) S(t-1) <= 24; WAITV(16)
    // additionally drains S(t-2) (retires fast) -- stronger, still correct,
    // and does NOT constrain loads L(t+1)/L(t+2).
    int par = 1;                                    // t % 3
    for (int t = 1; t <= 59; ++t) {
        WAITV(16);
        read_x<NQ>(xv, xrd + par * XBUF);
        int par2 = par + 2; if (par2 >= 3) par2 -= 3;
        load_tile<NQ>(xl + (size_t)(t + 2) * CH, shx + par2 * XBUF);
        lif_tile<NQ>(xv, shrow, alpha, beta, vth, mem, vdiff, spk);
        store_tile(sh, sub, off, outp + (size_t)t * CH);
        if (++par == 3) par = 0;
    }
    // t=60, buffer 0. After L(60): S(58) L(61) S(59) -> WAITV(16) stronger-ok.
    WAITV(16);
    read_x<NQ>(xv, xrd + 0 * XBUF);
    load_tile<TAILQ>(xl + (size_t)62 * CH, shx + 2 * XBUF);  // Ltail -> buf 2
    lif_tile<NQ>(xv, shrow, alpha, beta, vth, mem, vdiff, spk);
    store_tile(sh, sub, off, outp + (size_t)60 * CH);

    // t=61, buffer 1. After L(61): S(59) Ltail(4) S(60) -> WAITV(12) ok.
    WAITV(12);
    read_x<NQ>(xv, xrd + 1 * XBUF);
    lif_tile<NQ>(xv, shrow, alpha, beta, vth, mem, vdiff, spk);
    store_tile(sh, sub, off, outp + (size_t)61 * CH);

    // tail (16 steps), buffer 2. After Ltail: S(60) S(61) -> WAITV(8) ok.
    WAITV(8);
    read_x<TAILQ>(xv, xrd + 2 * XBUF);
    lif_tile<TAILQ>(xv, shrow, alpha, beta, vth, mem, vdiff, spk);
    {   // tail store: 64B/row, 4 lanes/row, 16 rows/instr, 4 instrs (R6 code)
        const int subt = lane >> 2;                 // 0..15
        const int offt = lane & 3;                  // 0..3
        float* opt = out + (size_t)(row0 + subt) * T_LEN + NFULL * CH + offt * 4;
#pragma unroll
        for (int k = 0; k < 4; ++k) {
            const float* p = sh + (subt + 16*k) * LDSW + offt * 4;
            float4 s = make_float4(p[0], p[1], p[2], p[3]);
            *reinterpret_cast<float4*>(opt + (size_t)(16*k) * T_LEN) = s;
        }
    }
}

extern "C" void kernel_launch(void* const* d_in, const int* in_sizes, int n_in,
                              void* d_out, int out_size, void* d_ws, size_t ws_size,
                              hipStream_t stream) {
    const float* x     = (const float*)d_in[0];
    const float* alpha = (const float*)d_in[1];
    const float* beta  = (const float*)d_in[2];
    const float* vth   = (const float*)d_in[3];
    float* out = (float*)d_out;

    const int C    = in_sizes[3];            // 256
    const int rows = in_sizes[0] / T_LEN;    // B*C = 16384

    dim3 grid((rows + 63) / 64), block(64);
    lif_fwd_kernel<<<grid, block, 0, stream>>>(x, alpha, beta, vth, out, C, rows);
}